// Round 6
// baseline (562.097 us; speedup 1.0000x reference)
//
#include <hip/hip_runtime.h>

#define N_NODES 100000
#define N_EDGES 1600000
#define F_NODE  32
#define F_GLOB  16
#define HDIM    64
#define OUTDIM  64
#define GB      2048    // persistent blocks for dense GEMMs
#define SHARD_N 12500   // nodes per shard (100000/8)
#define PBLK    1024    // partition blocks
#define CHUNK   ((N_EDGES + PBLK - 1) / PBLK)   // 1563
#define EPT     ((CHUNK + 255) / 256)           // 7
#define SCAP    208000  // per-shard stage capacity (mean 200k, +19 sigma)
#define HB      64      // hist2 blocks per shard
#define SB2     128     // scatter2 blocks per shard

typedef unsigned short u16;
typedef unsigned int   u32;

__device__ __forceinline__ u16 f2b(float f) {            // fp32 -> bf16 RNE
    u32 u = __float_as_uint(f);
    return (u16)((u + 0x7fffu + ((u >> 16) & 1u)) >> 16);
}
__device__ __forceinline__ float blo(u32 p) { return __uint_as_float(p << 16); }
__device__ __forceinline__ float bhi(u32 p) { return __uint_as_float(p & 0xffff0000u); }

// ---------- CSR build (staged radix partition) ----------

// Pass A: partition edges into 8 dst-shard staging buffers, coalesced writes.
__global__ void __launch_bounds__(256)
k_part(const int* __restrict__ src, const int* __restrict__ dst,
       int* __restrict__ shcnt, int2* __restrict__ stage) {
    __shared__ int  lcnt[8];
    __shared__ int  lofs[9];
    __shared__ int  gbase[8];
    __shared__ int2 lbuf[CHUNK];
    int t = threadIdx.x;
    if (t < 8) lcnt[t] = 0;
    __syncthreads();
    int e0 = blockIdx.x * CHUNK;
    int n = N_EDGES - e0; if (n > CHUNK) n = CHUNK; if (n < 0) n = 0;
    int2 ev[EPT]; int rk[EPT]; int sh[EPT];
    #pragma unroll
    for (int j = 0; j < EPT; ++j) {
        int i = t + j * 256;
        if (i < n) {
            int sv = __builtin_nontemporal_load(&src[e0 + i]);
            int dv = __builtin_nontemporal_load(&dst[e0 + i]);
            int k = dv / SHARD_N;
            ev[j] = make_int2(sv, dv);
            sh[j] = k;
            rk[j] = atomicAdd(&lcnt[k], 1);
        }
    }
    __syncthreads();
    if (t == 0) {
        int run = 0;
        #pragma unroll
        for (int k = 0; k < 8; ++k) { lofs[k] = run; run += lcnt[k]; }
        lofs[8] = run;
    }
    __syncthreads();
    if (t < 8) gbase[t] = atomicAdd(&shcnt[t], lcnt[t]);
    __syncthreads();
    #pragma unroll
    for (int j = 0; j < EPT; ++j) {
        int i = t + j * 256;
        if (i < n) lbuf[lofs[sh[j]] + rk[j]] = ev[j];
    }
    __syncthreads();
    for (int i = t; i < n; i += 256) {
        int k = 0;
        #pragma unroll
        for (int q = 1; q < 8; ++q) if (i >= lofs[q]) k = q;
        int p = gbase[k] + (i - lofs[k]);
        if (p < SCAP) stage[(size_t)k * SCAP + p] = lbuf[i];
    }
}

// Pass B1: degree histogram from staged pairs; cnt atomics land in a 50 KB
// per-shard window resident in that XCD's L2.
__global__ void k_hist2(const int2* __restrict__ stage, const int* __restrict__ shcnt,
                        int* __restrict__ cnt) {
    int s = blockIdx.x & 7;
    int n = shcnt[s]; if (n > SCAP) n = SCAP;
    const int2* st = stage + (size_t)s * SCAP;
    for (int p = (blockIdx.x >> 3) * 256 + threadIdx.x; p < n; p += HB * 256)
        atomicAdd(&cnt[st[p].y], 1);
}

// scan1 + dis fused
__global__ void k_scan1(const int* __restrict__ cnt, int* __restrict__ rowptr,
                        int* __restrict__ bsum, float* __restrict__ dis) {
    __shared__ int lds[256];
    int t = threadIdx.x;
    int i = blockIdx.x * 256 + t;
    int v = (i < N_NODES) ? cnt[i] : 0;
    if (i < N_NODES) dis[i] = rsqrtf((float)(v + 1));   // +1 self-loop
    int x = v;
    lds[t] = x;
    __syncthreads();
    for (int ofs = 1; ofs < 256; ofs <<= 1) {
        int y = (t >= ofs) ? lds[t - ofs] : 0;
        __syncthreads();
        x += y;
        lds[t] = x;
        __syncthreads();
    }
    if (i < N_NODES) rowptr[i] = x - v;
    if (t == 255)    bsum[blockIdx.x] = x;
}

__global__ void k_scan2(int* __restrict__ bsum, int nb, int* __restrict__ rowptr) {
    __shared__ int lds[512];
    int t = threadIdx.x;
    int v = (t < nb) ? bsum[t] : 0;
    int x = v;
    lds[t] = x;
    __syncthreads();
    for (int ofs = 1; ofs < 512; ofs <<= 1) {
        int y = (t >= ofs) ? lds[t - ofs] : 0;
        __syncthreads();
        x += y;
        lds[t] = x;
        __syncthreads();
    }
    if (t < nb) bsum[t] = x - v;
    if (t == 0) rowptr[N_NODES] = N_EDGES;
}

__global__ void k_scan3(int* __restrict__ rowptr, const int* __restrict__ bsum) {
    int i = blockIdx.x * 256 + threadIdx.x;
    if (i < N_NODES) rowptr[i] += bsum[blockIdx.x];
}

// Pass B2: scatter col from staged pairs; all random traffic (fill atomics,
// col stores) confined to the shard's L2-resident windows; reads sequential.
__global__ void k_scatter2(const int2* __restrict__ stage, const int* __restrict__ shcnt,
                           const int* __restrict__ rowptr, int* __restrict__ fill,
                           int* __restrict__ col) {
    int s = blockIdx.x & 7;
    int n = shcnt[s]; if (n > SCAP) n = SCAP;
    const int2* st = stage + (size_t)s * SCAP;
    for (int p = (blockIdx.x >> 3) * 256 + threadIdx.x; p < n; p += SB2 * 256) {
        int2 ed = st[p];
        int pos = rowptr[ed.y] + atomicAdd(&fill[ed.y], 1);
        col[pos] = ed.x;
    }
}

// ---------- dense kernels (persistent, weights in LDS once) ----------

// layer 0 fused: hw(bf16) = dis * ((x @ wn + bn) @ wc)
__global__ void __launch_bounds__(256)
k_embed_p(const float* __restrict__ x, const float* __restrict__ wn,
          const float* __restrict__ bn, const float* __restrict__ wc,
          const float* __restrict__ dis, u16* __restrict__ hw) {
    __shared__ float wnl[F_NODE * HDIM];
    __shared__ float wcl[HDIM * HDIM];
    __shared__ float xs[4][4 * F_NODE];
    __shared__ float ts[4][4 * HDIM];
    int t = threadIdx.x;
    for (int i = t; i < F_NODE * HDIM; i += 256) wnl[i] = wn[i];
    for (int i = t; i < HDIM * HDIM; i += 256)   wcl[i] = wc[i];
    __syncthreads();
    int wid = t >> 6, lane = t & 63;
    float bnv = bn[lane];
    int gw = blockIdx.x * 4 + wid;
    const int nw = GB * 4;
    for (int c0 = gw * 4; c0 < N_NODES; c0 += nw * 4) {
        ((float2*)xs[wid])[lane] = ((const float2*)&x[(size_t)c0 * F_NODE])[lane];
        #pragma unroll
        for (int r = 0; r < 4; ++r) {
            float acc = bnv;
            #pragma unroll
            for (int k = 0; k < F_NODE; k += 4) {
                float4 xb = *(const float4*)&xs[wid][r * F_NODE + k];
                acc += xb.x * wnl[(k + 0) * HDIM + lane]
                     + xb.y * wnl[(k + 1) * HDIM + lane]
                     + xb.z * wnl[(k + 2) * HDIM + lane]
                     + xb.w * wnl[(k + 3) * HDIM + lane];
            }
            ts[wid][r * HDIM + lane] = acc;
        }
        float a0 = 0.f, a1 = 0.f, a2 = 0.f, a3 = 0.f;
        #pragma unroll
        for (int k = 0; k < HDIM; k += 4) {
            float4 x0 = *(const float4*)&ts[wid][0 * HDIM + k];
            float4 x1 = *(const float4*)&ts[wid][1 * HDIM + k];
            float4 x2 = *(const float4*)&ts[wid][2 * HDIM + k];
            float4 x3 = *(const float4*)&ts[wid][3 * HDIM + k];
            float w0 = wcl[(k + 0) * HDIM + lane];
            float w1 = wcl[(k + 1) * HDIM + lane];
            float w2 = wcl[(k + 2) * HDIM + lane];
            float w3 = wcl[(k + 3) * HDIM + lane];
            a0 += x0.x * w0 + x0.y * w1 + x0.z * w2 + x0.w * w3;
            a1 += x1.x * w0 + x1.y * w1 + x1.z * w2 + x1.w * w3;
            a2 += x2.x * w0 + x2.y * w1 + x2.z * w2 + x2.w * w3;
            a3 += x3.x * w0 + x3.y * w1 + x3.z * w2 + x3.w * w3;
        }
        float4 dv = *(const float4*)&dis[c0];
        hw[(size_t)(c0 + 0) * HDIM + lane] = f2b(dv.x * a0);
        hw[(size_t)(c0 + 1) * HDIM + lane] = f2b(dv.y * a1);
        hw[(size_t)(c0 + 2) * HDIM + lane] = f2b(dv.z * a2);
        hw[(size_t)(c0 + 3) * HDIM + lane] = f2b(dv.w * a3);
    }
}

// hw(bf16) = dis * (h(bf16) @ w), persistent
__global__ void __launch_bounds__(256)
k_gemm_p(const u16* __restrict__ h, const float* __restrict__ w,
         const float* __restrict__ dis, u16* __restrict__ hw) {
    __shared__ float wl[HDIM * HDIM];
    __shared__ float xs[4][4 * HDIM];
    int t = threadIdx.x;
    for (int i = t; i < HDIM * HDIM; i += 256) wl[i] = w[i];
    __syncthreads();
    int wid = t >> 6, lane = t & 63;
    int gw = blockIdx.x * 4 + wid;
    const int nw = GB * 4;
    for (int c0 = gw * 4; c0 < N_NODES; c0 += nw * 4) {
        uint2 rv = ((const uint2*)(h + (size_t)c0 * HDIM))[lane];  // 4 bf16
        float4 xf;
        xf.x = blo(rv.x); xf.y = bhi(rv.x);
        xf.z = blo(rv.y); xf.w = bhi(rv.y);
        ((float4*)xs[wid])[lane] = xf;
        float a0 = 0.f, a1 = 0.f, a2 = 0.f, a3 = 0.f;
        #pragma unroll
        for (int k = 0; k < HDIM; k += 4) {
            float4 x0 = *(const float4*)&xs[wid][0 * HDIM + k];
            float4 x1 = *(const float4*)&xs[wid][1 * HDIM + k];
            float4 x2 = *(const float4*)&xs[wid][2 * HDIM + k];
            float4 x3 = *(const float4*)&xs[wid][3 * HDIM + k];
            float w0 = wl[(k + 0) * HDIM + lane];
            float w1 = wl[(k + 1) * HDIM + lane];
            float w2 = wl[(k + 2) * HDIM + lane];
            float w3 = wl[(k + 3) * HDIM + lane];
            a0 += x0.x * w0 + x0.y * w1 + x0.z * w2 + x0.w * w3;
            a1 += x1.x * w0 + x1.y * w1 + x1.z * w2 + x1.w * w3;
            a2 += x2.x * w0 + x2.y * w1 + x2.z * w2 + x2.w * w3;
            a3 += x3.x * w0 + x3.y * w1 + x3.z * w2 + x3.w * w3;
        }
        float4 dv = *(const float4*)&dis[c0];
        hw[(size_t)(c0 + 0) * HDIM + lane] = f2b(dv.x * a0);
        hw[(size_t)(c0 + 1) * HDIM + lane] = f2b(dv.y * a1);
        hw[(size_t)(c0 + 2) * HDIM + lane] = f2b(dv.z * a2);
        hw[(size_t)(c0 + 3) * HDIM + lane] = f2b(dv.w * a3);
    }
}

// ---------- pull aggregation (bf16 rows = 128B; 8 lanes/row; 2x unrolled) ----------

__global__ void __launch_bounds__(256)
k_pull(const u16* __restrict__ hw, const int* __restrict__ rowptr,
       const int* __restrict__ col, const float* __restrict__ dis,
       const float* __restrict__ b, u16* __restrict__ hout) {
    int wid = threadIdx.x >> 6, lane = threadIdx.x & 63;
    int v = blockIdx.x * 4 + wid;
    if (v >= N_NODES) return;
    int g = lane >> 3, sub = lane & 7;      // g: edge slot, sub: 8-feature chunk
    float acc[8] = {0.f, 0.f, 0.f, 0.f, 0.f, 0.f, 0.f, 0.f};
    int s0 = rowptr[v], s1 = rowptr[v + 1];
    for (int base = s0; base < s1; base += 64) {
        int m = s1 - base; if (m > 64) m = 64;
        int c = 0;
        if (lane < m) c = col[base + lane];
        for (int i = 0; i < m; i += 16) {
            int cs0 = __shfl(c, i + g);
            int cs1 = __shfl(c, i + 8 + g);
            bool p0 = (i + g < m), p1 = (i + 8 + g < m);
            uint4 a0, a1;
            if (p0) a0 = *(const uint4*)(hw + (size_t)cs0 * HDIM + sub * 8);
            if (p1) a1 = *(const uint4*)(hw + (size_t)cs1 * HDIM + sub * 8);
            if (p0) {
                acc[0] += blo(a0.x); acc[1] += bhi(a0.x);
                acc[2] += blo(a0.y); acc[3] += bhi(a0.y);
                acc[4] += blo(a0.z); acc[5] += bhi(a0.z);
                acc[6] += blo(a0.w); acc[7] += bhi(a0.w);
            }
            if (p1) {
                acc[0] += blo(a1.x); acc[1] += bhi(a1.x);
                acc[2] += blo(a1.y); acc[3] += bhi(a1.y);
                acc[4] += blo(a1.z); acc[5] += bhi(a1.z);
                acc[6] += blo(a1.w); acc[7] += bhi(a1.w);
            }
        }
    }
    #pragma unroll
    for (int k = 0; k < 8; ++k) {
        acc[k] += __shfl_xor(acc[k], 8);
        acc[k] += __shfl_xor(acc[k], 16);
        acc[k] += __shfl_xor(acc[k], 32);
    }
    uint4 sv = *(const uint4*)(hw + (size_t)v * HDIM + sub * 8);   // self row
    float se[8];
    se[0] = blo(sv.x); se[1] = bhi(sv.x); se[2] = blo(sv.y); se[3] = bhi(sv.y);
    se[4] = blo(sv.z); se[5] = bhi(sv.z); se[6] = blo(sv.w); se[7] = bhi(sv.w);
    float4 b0 = *(const float4*)&b[sub * 8];
    float4 b1 = *(const float4*)&b[sub * 8 + 4];
    float bb[8] = {b0.x, b0.y, b0.z, b0.w, b1.x, b1.y, b1.z, b1.w};
    float dv = dis[v];
    u32 r[8];
    #pragma unroll
    for (int k = 0; k < 8; ++k) {
        float val = fmaxf(bb[k] + dv * (acc[k] + se[k]), 0.f);
        u32 u = __float_as_uint(val);
        r[k] = (u + 0x7fffu + ((u >> 16) & 1u)) >> 16;
    }
    uint4 pk;
    pk.x = r[0] | (r[1] << 16); pk.y = r[2] | (r[3] << 16);
    pk.z = r[4] | (r[5] << 16); pk.w = r[6] | (r[7] << 16);
    if (g == 0) *(uint4*)(hout + (size_t)v * HDIM + sub * 8) = pk;
}

// ---------- readout ----------

__global__ void k_mean(const u16* __restrict__ h, float* __restrict__ partial) {
    __shared__ float lds[256];
    int t = threadIdx.x;
    int f = t & 63, g = t >> 6;
    float acc = 0.f;
    for (int v = blockIdx.x * 4 + g; v < N_NODES; v += gridDim.x * 4)
        acc += __uint_as_float((u32)h[(size_t)v * HDIM + f] << 16);
    lds[t] = acc;
    __syncthreads();
    if (t < 64)
        partial[blockIdx.x * 64 + t] = lds[t] + lds[t + 64] + lds[t + 128] + lds[t + 192];
}

__global__ void k_final(const float* __restrict__ partial, int nparts,
                        const float* __restrict__ gfeat,
                        const float* __restrict__ wg, const float* __restrict__ bg,
                        const float* __restrict__ w1, const float* __restrict__ b1,
                        const float* __restrict__ w2, const float* __restrict__ b2,
                        float* __restrict__ out) {
    __shared__ float xc[2 * HDIM];
    __shared__ float hid[HDIM];
    int t = threadIdx.x;   // 64 threads
    float s = 0.f;
    for (int p = 0; p < nparts; ++p) s += partial[p * 64 + t];
    xc[t] = s / (float)N_NODES;
    float gacc = bg[t];
    for (int k = 0; k < F_GLOB; ++k) gacc += gfeat[k] * wg[k * HDIM + t];
    xc[HDIM + t] = fmaxf(gacc, 0.f);
    __syncthreads();
    float hacc = b1[t];
    for (int k = 0; k < 2 * HDIM; ++k) hacc += xc[k] * w1[k * HDIM + t];
    hid[t] = fmaxf(hacc, 0.f);
    __syncthreads();
    float oacc = b2[t];
    for (int k = 0; k < HDIM; ++k) oacc += hid[k] * w2[k * OUTDIM + t];
    out[t] = oacc;
}

// ---------- launch ----------

extern "C" void kernel_launch(void* const* d_in, const int* in_sizes, int n_in,
                              void* d_out, int out_size, void* d_ws, size_t ws_size,
                              hipStream_t stream) {
    const float* x      = (const float*)d_in[0];
    const int*   eidx   = (const int*)d_in[1];
    const float* gfeat  = (const float*)d_in[2];
    const float* w_node = (const float*)d_in[3];
    const float* b_node = (const float*)d_in[4];
    const float* w_glob = (const float*)d_in[5];
    const float* b_glob = (const float*)d_in[6];
    const float* w_c[3] = {(const float*)d_in[7], (const float*)d_in[9], (const float*)d_in[11]};
    const float* b_c[3] = {(const float*)d_in[8], (const float*)d_in[10], (const float*)d_in[12]};
    const float* w_fc1  = (const float*)d_in[13];
    const float* b_fc1  = (const float*)d_in[14];
    const float* w_fc2  = (const float*)d_in[15];
    const float* b_fc2  = (const float*)d_in[16];
    float* out = (float*)d_out;

    const int* srcp = eidx;
    const int* dstp = eidx + N_EDGES;

    char* ws = (char*)d_ws;
    size_t off = 0;
    auto alloc = [&](size_t bytes) -> void* {
        void* p = ws + off;
        off = (off + bytes + 255) & ~(size_t)255;
        return p;
    };
    int*   cnt     = (int*)  alloc((size_t)N_NODES * 4);
    int*   rowptr  = (int*)  alloc((size_t)(N_NODES + 1) * 4);
    int*   fill    = (int*)  alloc((size_t)N_NODES * 4);
    int*   bsum    = (int*)  alloc(512 * 4);
    int*   shcnt   = (int*)  alloc(8 * 4);
    float* dis     = (float*)alloc((size_t)N_NODES * 4);
    int*   col     = (int*)  alloc((size_t)N_EDGES * 4);
    int2*  stage   = (int2*) alloc((size_t)8 * SCAP * 8);
    u16*   hbuf    = (u16*)  alloc((size_t)N_NODES * HDIM * 2);
    u16*   hwbuf   = (u16*)  alloc((size_t)N_NODES * HDIM * 2);
    float* partial = (float*)alloc(256 * 64 * 4);

    hipMemsetAsync(cnt,   0, (size_t)N_NODES * 4, stream);
    hipMemsetAsync(fill,  0, (size_t)N_NODES * 4, stream);
    hipMemsetAsync(shcnt, 0, 8 * 4, stream);

    int nb = (N_NODES + 255) / 256;   // 391 (< 512, fits k_scan2)
    k_part    <<<PBLK, 256, 0, stream>>>(srcp, dstp, shcnt, stage);
    k_hist2   <<<8 * HB, 256, 0, stream>>>(stage, shcnt, cnt);
    k_scan1   <<<nb, 256, 0, stream>>>(cnt, rowptr, bsum, dis);
    k_scan2   <<<1, 512, 0, stream>>>(bsum, nb, rowptr);
    k_scan3   <<<nb, 256, 0, stream>>>(rowptr, bsum);
    k_scatter2<<<8 * SB2, 256, 0, stream>>>(stage, shcnt, rowptr, fill, col);

    int pb = (N_NODES + 3) / 4;       // 25000 blocks, 1 node per wave

    k_embed_p<<<GB, 256, 0, stream>>>(x, w_node, b_node, w_c[0], dis, hwbuf);
    k_pull   <<<pb, 256, 0, stream>>>(hwbuf, rowptr, col, dis, b_c[0], hbuf);
    for (int l = 1; l < 3; ++l) {
        k_gemm_p<<<GB, 256, 0, stream>>>(hbuf, w_c[l], dis, hwbuf);
        k_pull  <<<pb, 256, 0, stream>>>(hwbuf, rowptr, col, dis, b_c[l], hbuf);
    }
    k_mean <<<256, 256, 0, stream>>>(hbuf, partial);
    k_final<<<1, 64, 0, stream>>>(partial, 256, gfeat, w_glob, b_glob,
                                  w_fc1, b_fc1, w_fc2, b_fc2, out);
}

// Round 9
// 392.592 us; speedup vs baseline: 1.4318x; 1.4318x over previous
//
#include <hip/hip_runtime.h>

#define N_NODES 100000
#define N_EDGES 1600000
#define F_NODE  32
#define F_GLOB  16
#define HDIM    64
#define OUTDIM  64
#define GB      2048    // persistent blocks for dense GEMMs
#define PBLK    512     // partition blocks
#define CHUNK   3125    // edges per partition block (512*3125 = 1.6M exactly)
#define EPT     13      // ceil(CHUNK/256)
#define NSH     128     // dst shards
#define SHN     782     // nodes per shard (ceil(100000/128))
#define SCAP    13568   // per-shard stage capacity (mean 12500, +9 sigma)

typedef unsigned short u16;
typedef unsigned int   u32;

__device__ __forceinline__ u16 f2b(float f) {            // fp32 -> bf16 RNE
    u32 u = __float_as_uint(f);
    return (u16)((u + 0x7fffu + ((u >> 16) & 1u)) >> 16);
}
__device__ __forceinline__ float blo(u32 p) { return __uint_as_float(p << 16); }
__device__ __forceinline__ float bhi(u32 p) { return __uint_as_float(p & 0xffff0000u); }

// ---------- CSR build: partition -> per-shard LDS counting sort ----------

// Pass A: partition edges into 128 dst-shard staging buffers.
// Only 128 global atomics per block (bucket reservations); per-edge ranks via LDS.
__global__ void __launch_bounds__(256)
k_part(const int* __restrict__ src, const int* __restrict__ dst,
       int* __restrict__ shcnt, int2* __restrict__ stage) {
    __shared__ int lcnt[NSH];
    __shared__ int gbase[NSH];
    int t = threadIdx.x;
    for (int i = t; i < NSH; i += 256) lcnt[i] = 0;
    __syncthreads();
    int e0 = blockIdx.x * CHUNK;
    int n = N_EDGES - e0; if (n > CHUNK) n = CHUNK; if (n < 0) n = 0;
    int2 ev[EPT]; int rk[EPT]; int sh[EPT];
    #pragma unroll
    for (int j = 0; j < EPT; ++j) {
        int i = t + j * 256;
        if (i < n) {
            int sv = __builtin_nontemporal_load(&src[e0 + i]);
            int dv = __builtin_nontemporal_load(&dst[e0 + i]);
            int k = dv / SHN;
            ev[j] = make_int2(sv, dv);
            sh[j] = k;
            rk[j] = atomicAdd(&lcnt[k], 1);
        }
    }
    __syncthreads();
    for (int i = t; i < NSH; i += 256)
        gbase[i] = atomicAdd(&shcnt[i], lcnt[i]);
    __syncthreads();
    #pragma unroll
    for (int j = 0; j < EPT; ++j) {
        int i = t + j * 256;
        if (i < n) {
            int p = gbase[sh[j]] + rk[j];
            if (p < SCAP) stage[(size_t)sh[j] * SCAP + p] = ev[j];
        }
    }
}

// Pass B: one block per shard. LDS histogram -> LDS scan -> rowptr/dis,
// then LDS-ranked scatter of col into the shard's ~50 KB L2-resident slice.
// Zero per-edge global atomics.
__global__ void __launch_bounds__(1024)
k_build(const int2* __restrict__ stage, const int* __restrict__ shcnt,
        int* __restrict__ rowptr, float* __restrict__ dis, int* __restrict__ col) {
    __shared__ int shc[NSH];
    __shared__ int hist[1024];
    __shared__ int A[1024];
    __shared__ int B[1024];
    int t = threadIdx.x;
    int s = blockIdx.x;
    if (t < NSH) shc[t] = shcnt[t];
    hist[t] = 0;
    __syncthreads();
    int sb = 0;                                  // global edge base of this shard
    for (int q = 0; q < s; ++q) sb += shc[q];
    int n = shc[s]; if (n > SCAP) n = SCAP;
    const int2* st = stage + (size_t)s * SCAP;
    int v0 = s * SHN;
    for (int p = t; p < n; p += 1024)
        atomicAdd(&hist[st[p].y - v0], 1);       // LDS atomics only
    __syncthreads();
    A[t] = hist[t];
    __syncthreads();
    int* cur = A; int* nxt = B;                  // Hillis-Steele inclusive scan
    for (int ofs = 1; ofs < 1024; ofs <<= 1) {
        nxt[t] = cur[t] + (t >= ofs ? cur[t - ofs] : 0);
        __syncthreads();
        int* tmp = cur; cur = nxt; nxt = tmp;
    }
    int v = v0 + t;
    if (t < SHN && v < N_NODES) {
        rowptr[v] = sb + cur[t] - hist[t];       // exclusive
        dis[v] = rsqrtf((float)(hist[t] + 1));   // +1 self-loop
    }
    if (s == NSH - 1 && t == 0) rowptr[N_NODES] = N_EDGES;
    nxt[t] = sb + cur[t] - hist[t];              // mutable fill cursor
    __syncthreads();
    for (int p = t; p < n; p += 1024) {
        int2 ed = st[p];
        int slot = atomicAdd(&nxt[ed.y - v0], 1);  // LDS rank
        col[slot] = ed.x;
    }
}

// ---------- dense kernels (persistent, weights in LDS once) ----------

// layer 0 fused: hw(bf16) = dis * ((x @ wn + bn) @ wc)
__global__ void __launch_bounds__(256)
k_embed_p(const float* __restrict__ x, const float* __restrict__ wn,
          const float* __restrict__ bn, const float* __restrict__ wc,
          const float* __restrict__ dis, u16* __restrict__ hw) {
    __shared__ float wnl[F_NODE * HDIM];
    __shared__ float wcl[HDIM * HDIM];
    __shared__ float xs[4][4 * F_NODE];
    __shared__ float ts[4][4 * HDIM];
    int t = threadIdx.x;
    for (int i = t; i < F_NODE * HDIM; i += 256) wnl[i] = wn[i];
    for (int i = t; i < HDIM * HDIM; i += 256)   wcl[i] = wc[i];
    __syncthreads();
    int wid = t >> 6, lane = t & 63;
    float bnv = bn[lane];
    int gw = blockIdx.x * 4 + wid;
    const int nw = GB * 4;
    for (int c0 = gw * 4; c0 < N_NODES; c0 += nw * 4) {
        ((float2*)xs[wid])[lane] = ((const float2*)&x[(size_t)c0 * F_NODE])[lane];
        #pragma unroll
        for (int r = 0; r < 4; ++r) {
            float acc = bnv;
            #pragma unroll
            for (int k = 0; k < F_NODE; k += 4) {
                float4 xb = *(const float4*)&xs[wid][r * F_NODE + k];
                acc += xb.x * wnl[(k + 0) * HDIM + lane]
                     + xb.y * wnl[(k + 1) * HDIM + lane]
                     + xb.z * wnl[(k + 2) * HDIM + lane]
                     + xb.w * wnl[(k + 3) * HDIM + lane];
            }
            ts[wid][r * HDIM + lane] = acc;
        }
        float a0 = 0.f, a1 = 0.f, a2 = 0.f, a3 = 0.f;
        #pragma unroll
        for (int k = 0; k < HDIM; k += 4) {
            float4 x0 = *(const float4*)&ts[wid][0 * HDIM + k];
            float4 x1 = *(const float4*)&ts[wid][1 * HDIM + k];
            float4 x2 = *(const float4*)&ts[wid][2 * HDIM + k];
            float4 x3 = *(const float4*)&ts[wid][3 * HDIM + k];
            float w0 = wcl[(k + 0) * HDIM + lane];
            float w1 = wcl[(k + 1) * HDIM + lane];
            float w2 = wcl[(k + 2) * HDIM + lane];
            float w3 = wcl[(k + 3) * HDIM + lane];
            a0 += x0.x * w0 + x0.y * w1 + x0.z * w2 + x0.w * w3;
            a1 += x1.x * w0 + x1.y * w1 + x1.z * w2 + x1.w * w3;
            a2 += x2.x * w0 + x2.y * w1 + x2.z * w2 + x2.w * w3;
            a3 += x3.x * w0 + x3.y * w1 + x3.z * w2 + x3.w * w3;
        }
        float4 dv = *(const float4*)&dis[c0];
        hw[(size_t)(c0 + 0) * HDIM + lane] = f2b(dv.x * a0);
        hw[(size_t)(c0 + 1) * HDIM + lane] = f2b(dv.y * a1);
        hw[(size_t)(c0 + 2) * HDIM + lane] = f2b(dv.z * a2);
        hw[(size_t)(c0 + 3) * HDIM + lane] = f2b(dv.w * a3);
    }
}

// hw(bf16) = dis * (h(bf16) @ w), persistent
__global__ void __launch_bounds__(256)
k_gemm_p(const u16* __restrict__ h, const float* __restrict__ w,
         const float* __restrict__ dis, u16* __restrict__ hw) {
    __shared__ float wl[HDIM * HDIM];
    __shared__ float xs[4][4 * HDIM];
    int t = threadIdx.x;
    for (int i = t; i < HDIM * HDIM; i += 256) wl[i] = w[i];
    __syncthreads();
    int wid = t >> 6, lane = t & 63;
    int gw = blockIdx.x * 4 + wid;
    const int nw = GB * 4;
    for (int c0 = gw * 4; c0 < N_NODES; c0 += nw * 4) {
        uint2 rv = ((const uint2*)(h + (size_t)c0 * HDIM))[lane];  // 4 bf16
        float4 xf;
        xf.x = blo(rv.x); xf.y = bhi(rv.x);
        xf.z = blo(rv.y); xf.w = bhi(rv.y);
        ((float4*)xs[wid])[lane] = xf;
        float a0 = 0.f, a1 = 0.f, a2 = 0.f, a3 = 0.f;
        #pragma unroll
        for (int k = 0; k < HDIM; k += 4) {
            float4 x0 = *(const float4*)&xs[wid][0 * HDIM + k];
            float4 x1 = *(const float4*)&xs[wid][1 * HDIM + k];
            float4 x2 = *(const float4*)&xs[wid][2 * HDIM + k];
            float4 x3 = *(const float4*)&xs[wid][3 * HDIM + k];
            float w0 = wl[(k + 0) * HDIM + lane];
            float w1 = wl[(k + 1) * HDIM + lane];
            float w2 = wl[(k + 2) * HDIM + lane];
            float w3 = wl[(k + 3) * HDIM + lane];
            a0 += x0.x * w0 + x0.y * w1 + x0.z * w2 + x0.w * w3;
            a1 += x1.x * w0 + x1.y * w1 + x1.z * w2 + x1.w * w3;
            a2 += x2.x * w0 + x2.y * w1 + x2.z * w2 + x2.w * w3;
            a3 += x3.x * w0 + x3.y * w1 + x3.z * w2 + x3.w * w3;
        }
        float4 dv = *(const float4*)&dis[c0];
        hw[(size_t)(c0 + 0) * HDIM + lane] = f2b(dv.x * a0);
        hw[(size_t)(c0 + 1) * HDIM + lane] = f2b(dv.y * a1);
        hw[(size_t)(c0 + 2) * HDIM + lane] = f2b(dv.z * a2);
        hw[(size_t)(c0 + 3) * HDIM + lane] = f2b(dv.w * a3);
    }
}

// ---------- pull aggregation (bf16 rows = 128B; 8 lanes/row; 2x unrolled) ----------

__global__ void __launch_bounds__(256)
k_pull(const u16* __restrict__ hw, const int* __restrict__ rowptr,
       const int* __restrict__ col, const float* __restrict__ dis,
       const float* __restrict__ b, u16* __restrict__ hout) {
    int wid = threadIdx.x >> 6, lane = threadIdx.x & 63;
    int v = blockIdx.x * 4 + wid;
    if (v >= N_NODES) return;
    int g = lane >> 3, sub = lane & 7;      // g: edge slot, sub: 8-feature chunk
    float acc[8] = {0.f, 0.f, 0.f, 0.f, 0.f, 0.f, 0.f, 0.f};
    int s0 = rowptr[v], s1 = rowptr[v + 1];
    for (int base = s0; base < s1; base += 64) {
        int m = s1 - base; if (m > 64) m = 64;
        int c = 0;
        if (lane < m) c = col[base + lane];
        for (int i = 0; i < m; i += 16) {
            int cs0 = __shfl(c, i + g);
            int cs1 = __shfl(c, i + 8 + g);
            bool p0 = (i + g < m), p1 = (i + 8 + g < m);
            uint4 a0, a1;
            if (p0) a0 = *(const uint4*)(hw + (size_t)cs0 * HDIM + sub * 8);
            if (p1) a1 = *(const uint4*)(hw + (size_t)cs1 * HDIM + sub * 8);
            if (p0) {
                acc[0] += blo(a0.x); acc[1] += bhi(a0.x);
                acc[2] += blo(a0.y); acc[3] += bhi(a0.y);
                acc[4] += blo(a0.z); acc[5] += bhi(a0.z);
                acc[6] += blo(a0.w); acc[7] += bhi(a0.w);
            }
            if (p1) {
                acc[0] += blo(a1.x); acc[1] += bhi(a1.x);
                acc[2] += blo(a1.y); acc[3] += bhi(a1.y);
                acc[4] += blo(a1.z); acc[5] += bhi(a1.z);
                acc[6] += blo(a1.w); acc[7] += bhi(a1.w);
            }
        }
    }
    #pragma unroll
    for (int k = 0; k < 8; ++k) {
        acc[k] += __shfl_xor(acc[k], 8);
        acc[k] += __shfl_xor(acc[k], 16);
        acc[k] += __shfl_xor(acc[k], 32);
    }
    uint4 sv = *(const uint4*)(hw + (size_t)v * HDIM + sub * 8);   // self row
    float se[8];
    se[0] = blo(sv.x); se[1] = bhi(sv.x); se[2] = blo(sv.y); se[3] = bhi(sv.y);
    se[4] = blo(sv.z); se[5] = bhi(sv.z); se[6] = blo(sv.w); se[7] = bhi(sv.w);
    float4 b0 = *(const float4*)&b[sub * 8];
    float4 b1 = *(const float4*)&b[sub * 8 + 4];
    float bb[8] = {b0.x, b0.y, b0.z, b0.w, b1.x, b1.y, b1.z, b1.w};
    float dv = dis[v];
    u32 r[8];
    #pragma unroll
    for (int k = 0; k < 8; ++k) {
        float val = fmaxf(bb[k] + dv * (acc[k] + se[k]), 0.f);
        u32 u = __float_as_uint(val);
        r[k] = (u + 0x7fffu + ((u >> 16) & 1u)) >> 16;
    }
    uint4 pk;
    pk.x = r[0] | (r[1] << 16); pk.y = r[2] | (r[3] << 16);
    pk.z = r[4] | (r[5] << 16); pk.w = r[6] | (r[7] << 16);
    if (g == 0) *(uint4*)(hout + (size_t)v * HDIM + sub * 8) = pk;
}

// ---------- readout ----------

__global__ void k_mean(const u16* __restrict__ h, float* __restrict__ partial) {
    __shared__ float lds[256];
    int t = threadIdx.x;
    int f = t & 63, g = t >> 6;
    float acc = 0.f;
    for (int v = blockIdx.x * 4 + g; v < N_NODES; v += gridDim.x * 4)
        acc += __uint_as_float((u32)h[(size_t)v * HDIM + f] << 16);
    lds[t] = acc;
    __syncthreads();
    if (t < 64)
        partial[blockIdx.x * 64 + t] = lds[t] + lds[t + 64] + lds[t + 128] + lds[t + 192];
}

// 256 threads / 4 waves; k-loops split 4-way + LDS reduce (was 1 wave, 67 us)
__global__ void __launch_bounds__(256)
k_final(const float* __restrict__ partial,
        const float* __restrict__ gfeat,
        const float* __restrict__ wg, const float* __restrict__ bg,
        const float* __restrict__ w1, const float* __restrict__ b1,
        const float* __restrict__ w2, const float* __restrict__ b2,
        float* __restrict__ out) {
    __shared__ float red[4][HDIM];
    __shared__ float xc[2 * HDIM];
    __shared__ float hid[HDIM];
    int t = threadIdx.x, g = t >> 6, lane = t & 63;
    float s = 0.f;
    for (int p = g * 64; p < (g + 1) * 64; ++p) s += partial[p * 64 + lane];
    red[g][lane] = s;
    __syncthreads();
    if (g == 0) {
        xc[lane] = (red[0][lane] + red[1][lane] + red[2][lane] + red[3][lane])
                   / (float)N_NODES;
    } else if (g == 1) {
        float gacc = bg[lane];
        for (int k = 0; k < F_GLOB; ++k) gacc += gfeat[k] * wg[k * HDIM + lane];
        xc[HDIM + lane] = fmaxf(gacc, 0.f);
    }
    __syncthreads();
    float hacc = 0.f;
    for (int k = g * 32; k < (g + 1) * 32; ++k) hacc += xc[k] * w1[k * HDIM + lane];
    red[g][lane] = hacc;
    __syncthreads();
    if (g == 0)
        hid[lane] = fmaxf(b1[lane] + red[0][lane] + red[1][lane]
                          + red[2][lane] + red[3][lane], 0.f);
    __syncthreads();
    float oacc = 0.f;
    for (int k = g * 16; k < (g + 1) * 16; ++k) oacc += hid[k] * w2[k * OUTDIM + lane];
    red[g][lane] = oacc;
    __syncthreads();
    if (g == 0)
        out[lane] = b2[lane] + red[0][lane] + red[1][lane]
                  + red[2][lane] + red[3][lane];
}

// ---------- launch ----------

extern "C" void kernel_launch(void* const* d_in, const int* in_sizes, int n_in,
                              void* d_out, int out_size, void* d_ws, size_t ws_size,
                              hipStream_t stream) {
    const float* x      = (const float*)d_in[0];
    const int*   eidx   = (const int*)d_in[1];
    const float* gfeat  = (const float*)d_in[2];
    const float* w_node = (const float*)d_in[3];
    const float* b_node = (const float*)d_in[4];
    const float* w_glob = (const float*)d_in[5];
    const float* b_glob = (const float*)d_in[6];
    const float* w_c[3] = {(const float*)d_in[7], (const float*)d_in[9], (const float*)d_in[11]};
    const float* b_c[3] = {(const float*)d_in[8], (const float*)d_in[10], (const float*)d_in[12]};
    const float* w_fc1  = (const float*)d_in[13];
    const float* b_fc1  = (const float*)d_in[14];
    const float* w_fc2  = (const float*)d_in[15];
    const float* b_fc2  = (const float*)d_in[16];
    float* out = (float*)d_out;

    const int* srcp = eidx;
    const int* dstp = eidx + N_EDGES;

    char* ws = (char*)d_ws;
    size_t off = 0;
    auto alloc = [&](size_t bytes) -> void* {
        void* p = ws + off;
        off = (off + bytes + 255) & ~(size_t)255;
        return p;
    };
    int*   rowptr  = (int*)  alloc((size_t)(N_NODES + 1) * 4);
    int*   shcnt   = (int*)  alloc(NSH * 4);
    float* dis     = (float*)alloc((size_t)N_NODES * 4);
    int*   col     = (int*)  alloc((size_t)N_EDGES * 4);
    int2*  stage   = (int2*) alloc((size_t)NSH * SCAP * 8);
    u16*   hbuf    = (u16*)  alloc((size_t)N_NODES * HDIM * 2);
    u16*   hwbuf   = (u16*)  alloc((size_t)N_NODES * HDIM * 2);
    float* partial = (float*)alloc(256 * 64 * 4);

    hipMemsetAsync(shcnt, 0, NSH * 4, stream);

    k_part <<<PBLK, 256, 0, stream>>>(srcp, dstp, shcnt, stage);
    k_build<<<NSH, 1024, 0, stream>>>(stage, shcnt, rowptr, dis, col);

    int pb = (N_NODES + 3) / 4;       // 25000 blocks, 1 node per wave

    k_embed_p<<<GB, 256, 0, stream>>>(x, w_node, b_node, w_c[0], dis, hwbuf);
    k_pull   <<<pb, 256, 0, stream>>>(hwbuf, rowptr, col, dis, b_c[0], hbuf);
    for (int l = 1; l < 3; ++l) {
        k_gemm_p<<<GB, 256, 0, stream>>>(hbuf, w_c[l], dis, hwbuf);
        k_pull  <<<pb, 256, 0, stream>>>(hwbuf, rowptr, col, dis, b_c[l], hbuf);
    }
    k_mean <<<256, 256, 0, stream>>>(hbuf, partial);
    k_final<<<1, 256, 0, stream>>>(partial, gfeat, w_glob, b_glob,
                                   w_fc1, b_fc1, w_fc2, b_fc2, out);
}

// Round 10
// 324.225 us; speedup vs baseline: 1.7337x; 1.2109x over previous
//
#include <hip/hip_runtime.h>

#define N_NODES 100000
#define N_EDGES 1600000
#define F_NODE  32
#define F_GLOB  16
#define HDIM    64
#define OUTDIM  64
#define PBLK    512     // partition blocks
#define CHUNK   3125    // edges per partition block (512*3125 = 1.6M exactly)
#define EPT     13      // ceil(CHUNK/256)
#define NSH     128     // dst shards
#define SHN     782     // nodes per shard (ceil(100000/128))
#define SCAP    13568   // per-shard stage capacity (mean 12500, +9 sigma)
#define NTILE   (N_NODES / 16)   // 6250 MFMA row-tiles

typedef unsigned short u16;
typedef unsigned int   u32;
typedef __attribute__((ext_vector_type(8))) short short8v;  // 8 bf16 (4 VGPR)
typedef __attribute__((ext_vector_type(4))) float f32x4;    // MFMA acc

__device__ __forceinline__ u16 f2b(float f) {            // fp32 -> bf16 RNE
    u32 u = __float_as_uint(f);
    return (u16)((u + 0x7fffu + ((u >> 16) & 1u)) >> 16);
}
__device__ __forceinline__ float blo(u32 p) { return __uint_as_float(p << 16); }
__device__ __forceinline__ float bhi(u32 p) { return __uint_as_float(p & 0xffff0000u); }

// ---------- CSR build: partition -> per-shard LDS counting sort ----------

__global__ void __launch_bounds__(256)
k_part(const int* __restrict__ src, const int* __restrict__ dst,
       int* __restrict__ shcnt, int2* __restrict__ stage) {
    __shared__ int lcnt[NSH];
    __shared__ int gbase[NSH];
    int t = threadIdx.x;
    for (int i = t; i < NSH; i += 256) lcnt[i] = 0;
    __syncthreads();
    int e0 = blockIdx.x * CHUNK;
    int n = N_EDGES - e0; if (n > CHUNK) n = CHUNK; if (n < 0) n = 0;
    int2 ev[EPT]; int rk[EPT]; int sh[EPT];
    #pragma unroll
    for (int j = 0; j < EPT; ++j) {
        int i = t + j * 256;
        if (i < n) {
            int sv = __builtin_nontemporal_load(&src[e0 + i]);
            int dv = __builtin_nontemporal_load(&dst[e0 + i]);
            int k = dv / SHN;
            ev[j] = make_int2(sv, dv);
            sh[j] = k;
            rk[j] = atomicAdd(&lcnt[k], 1);
        }
    }
    __syncthreads();
    for (int i = t; i < NSH; i += 256)
        gbase[i] = atomicAdd(&shcnt[i], lcnt[i]);
    __syncthreads();
    #pragma unroll
    for (int j = 0; j < EPT; ++j) {
        int i = t + j * 256;
        if (i < n) {
            int p = gbase[sh[j]] + rk[j];
            if (p < SCAP) stage[(size_t)sh[j] * SCAP + p] = ev[j];
        }
    }
}

__global__ void __launch_bounds__(1024)
k_build(const int2* __restrict__ stage, const int* __restrict__ shcnt,
        int* __restrict__ rowptr, float* __restrict__ dis, int* __restrict__ col) {
    __shared__ int shc[NSH];
    __shared__ int hist[1024];
    __shared__ int A[1024];
    __shared__ int B[1024];
    int t = threadIdx.x;
    int s = blockIdx.x;
    if (t < NSH) shc[t] = shcnt[t];
    hist[t] = 0;
    __syncthreads();
    int sb = 0;
    for (int q = 0; q < s; ++q) sb += shc[q];
    int n = shc[s]; if (n > SCAP) n = SCAP;
    const int2* st = stage + (size_t)s * SCAP;
    int v0 = s * SHN;
    for (int p = t; p < n; p += 1024)
        atomicAdd(&hist[st[p].y - v0], 1);
    __syncthreads();
    A[t] = hist[t];
    __syncthreads();
    int* cur = A; int* nxt = B;
    for (int ofs = 1; ofs < 1024; ofs <<= 1) {
        nxt[t] = cur[t] + (t >= ofs ? cur[t - ofs] : 0);
        __syncthreads();
        int* tmp = cur; cur = nxt; nxt = tmp;
    }
    int v = v0 + t;
    if (t < SHN && v < N_NODES) {
        rowptr[v] = sb + cur[t] - hist[t];
        dis[v] = rsqrtf((float)(hist[t] + 1));
    }
    if (s == NSH - 1 && t == 0) rowptr[N_NODES] = N_EDGES;
    nxt[t] = sb + cur[t] - hist[t];
    __syncthreads();
    for (int p = t; p < n; p += 1024) {
        int2 ed = st[p];
        int slot = atomicAdd(&nxt[ed.y - v0], 1);
        col[slot] = ed.x;
    }
}

// ---------- x (f32) -> bf16 ----------

__global__ void __launch_bounds__(256)
k_cvt(const float* __restrict__ x, u16* __restrict__ xb) {
    int i = blockIdx.x * 256 + threadIdx.x;        // handles 8 elems
    if ((size_t)i * 8 >= (size_t)N_NODES * F_NODE) return;
    float4 a = ((const float4*)x)[i * 2];
    float4 b = ((const float4*)x)[i * 2 + 1];
    uint4 o;
    o.x = (u32)f2b(a.x) | ((u32)f2b(a.y) << 16);
    o.y = (u32)f2b(a.z) | ((u32)f2b(a.w) << 16);
    o.z = (u32)f2b(b.x) | ((u32)f2b(b.y) << 16);
    o.w = (u32)f2b(b.z) | ((u32)f2b(b.w) << 16);
    ((uint4*)xb)[i] = o;
}

// ---------- unified MFMA dense kernel: out(bf16 Nx64) = op(A(bf16 NxK) @ W(f32 Kx64)) ----------
// op: optionally +bias[col], optionally *dis[row].  16-row tile per wave.
// A-frag: lane l -> row=l&15, k=(l>>4)*8.. (+kb*32).  B-frag symmetric.
// C/D:    lane l -> col=l&15, row=(l>>4)*4+j   [verified m89 layout]

template<int K, bool BIAS, bool DIS>
__global__ void __launch_bounds__(256)
k_mfma(const u16* __restrict__ Amat, const float* __restrict__ W,
       const float* __restrict__ bias, const float* __restrict__ dis,
       u16* __restrict__ out) {
    int t = threadIdx.x, wid = t >> 6, l = t & 63;
    int tile = blockIdx.x * 4 + wid;
    if (tile >= NTILE) return;
    int lr = l & 15, kc = l >> 4;
    constexpr int KB = K / 32;
    // B fragments (weights, f32 -> bf16), registers only (fully unrolled)
    short8v bfrag[4][KB];
    #pragma unroll
    for (int ct = 0; ct < 4; ++ct)
        #pragma unroll
        for (int kb = 0; kb < KB; ++kb)
            #pragma unroll
            for (int j = 0; j < 8; ++j)
                bfrag[ct][kb][j] = (short)f2b(W[(kb * 32 + kc * 8 + j) * HDIM + ct * 16 + lr]);
    // A fragments
    int r0 = tile * 16;
    const u16* arow = Amat + (size_t)(r0 + lr) * K + kc * 8;
    short8v a[KB];
    #pragma unroll
    for (int kb = 0; kb < KB; ++kb)
        a[kb] = *(const short8v*)(arow + kb * 32);
    // MFMA accumulate
    f32x4 acc[4];
    #pragma unroll
    for (int ct = 0; ct < 4; ++ct) acc[ct] = (f32x4){0.f, 0.f, 0.f, 0.f};
    #pragma unroll
    for (int ct = 0; ct < 4; ++ct)
        #pragma unroll
        for (int kb = 0; kb < KB; ++kb)
            acc[ct] = __builtin_amdgcn_mfma_f32_16x16x32_bf16(a[kb], bfrag[ct][kb], acc[ct], 0, 0, 0);
    // epilogue
    float dv[4];
    #pragma unroll
    for (int j = 0; j < 4; ++j)
        dv[j] = DIS ? dis[r0 + kc * 4 + j] : 1.f;
    #pragma unroll
    for (int ct = 0; ct < 4; ++ct) {
        float bb = BIAS ? bias[ct * 16 + lr] : 0.f;
        #pragma unroll
        for (int j = 0; j < 4; ++j) {
            int row = r0 + kc * 4 + j;
            float val = acc[ct][j];
            if (BIAS) val += bb;
            if (DIS)  val *= dv[j];
            out[(size_t)row * HDIM + ct * 16 + lr] = f2b(val);
        }
    }
}

// ---------- pull v3: 8 nodes/wave, 8 lanes/node, lane owns 8 features ----------

__global__ void __launch_bounds__(256)
k_pull(const u16* __restrict__ hw, const int* __restrict__ rowptr,
       const int* __restrict__ col, const float* __restrict__ dis,
       const float* __restrict__ b, u16* __restrict__ hout) {
    int t = threadIdx.x, wid = t >> 6, lane = t & 63;
    int g = lane >> 3, sub = lane & 7;
    int v = blockIdx.x * 32 + wid * 8 + g;         // 3125*32 = 100000 exact
    const u16* hws = hw + sub * 8;
    // self row
    uint4 sv = *(const uint4*)(hws + (size_t)v * HDIM);
    float acc[8];
    acc[0] = blo(sv.x); acc[1] = bhi(sv.x);
    acc[2] = blo(sv.y); acc[3] = bhi(sv.y);
    acc[4] = blo(sv.z); acc[5] = bhi(sv.z);
    acc[6] = blo(sv.w); acc[7] = bhi(sv.w);
    int s0 = rowptr[v], s1 = rowptr[v + 1];
    int i = s0;
    for (; i + 2 <= s1; i += 2) {                  // 2-deep pipeline
        int c0 = col[i], c1 = col[i + 1];
        uint4 a0 = *(const uint4*)(hws + (size_t)c0 * HDIM);
        uint4 a1 = *(const uint4*)(hws + (size_t)c1 * HDIM);
        acc[0] += blo(a0.x); acc[1] += bhi(a0.x);
        acc[2] += blo(a0.y); acc[3] += bhi(a0.y);
        acc[4] += blo(a0.z); acc[5] += bhi(a0.z);
        acc[6] += blo(a0.w); acc[7] += bhi(a0.w);
        acc[0] += blo(a1.x); acc[1] += bhi(a1.x);
        acc[2] += blo(a1.y); acc[3] += bhi(a1.y);
        acc[4] += blo(a1.z); acc[5] += bhi(a1.z);
        acc[6] += blo(a1.w); acc[7] += bhi(a1.w);
    }
    if (i < s1) {
        int c0 = col[i];
        uint4 a0 = *(const uint4*)(hws + (size_t)c0 * HDIM);
        acc[0] += blo(a0.x); acc[1] += bhi(a0.x);
        acc[2] += blo(a0.y); acc[3] += bhi(a0.y);
        acc[4] += blo(a0.z); acc[5] += bhi(a0.z);
        acc[6] += blo(a0.w); acc[7] += bhi(a0.w);
    }
    float4 b0 = *(const float4*)&b[sub * 8];
    float4 b1 = *(const float4*)&b[sub * 8 + 4];
    float bb[8] = {b0.x, b0.y, b0.z, b0.w, b1.x, b1.y, b1.z, b1.w};
    float dv = dis[v];
    u32 r[8];
    #pragma unroll
    for (int k = 0; k < 8; ++k) {
        float val = fmaxf(bb[k] + dv * acc[k], 0.f);
        u32 u = __float_as_uint(val);
        r[k] = (u + 0x7fffu + ((u >> 16) & 1u)) >> 16;
    }
    uint4 pk;
    pk.x = r[0] | (r[1] << 16); pk.y = r[2] | (r[3] << 16);
    pk.z = r[4] | (r[5] << 16); pk.w = r[6] | (r[7] << 16);
    *(uint4*)(hout + (size_t)v * HDIM + sub * 8) = pk;   // 8 lanes x 16B = 128B/row
}

// ---------- readout ----------

__global__ void k_mean(const u16* __restrict__ h, float* __restrict__ partial) {
    __shared__ float lds[256];
    int t = threadIdx.x;
    int f = t & 63, g = t >> 6;
    float acc = 0.f;
    for (int v = blockIdx.x * 4 + g; v < N_NODES; v += gridDim.x * 4)
        acc += __uint_as_float((u32)h[(size_t)v * HDIM + f] << 16);
    lds[t] = acc;
    __syncthreads();
    if (t < 64)
        partial[blockIdx.x * 64 + t] = lds[t] + lds[t + 64] + lds[t + 128] + lds[t + 192];
}

__global__ void __launch_bounds__(256)
k_final(const float* __restrict__ partial,
        const float* __restrict__ gfeat,
        const float* __restrict__ wg, const float* __restrict__ bg,
        const float* __restrict__ w1, const float* __restrict__ b1,
        const float* __restrict__ w2, const float* __restrict__ b2,
        float* __restrict__ out) {
    __shared__ float red[4][HDIM];
    __shared__ float xc[2 * HDIM];
    __shared__ float hid[HDIM];
    int t = threadIdx.x, g = t >> 6, lane = t & 63;
    float s = 0.f;
    for (int p = g * 64; p < (g + 1) * 64; ++p) s += partial[p * 64 + lane];
    red[g][lane] = s;
    __syncthreads();
    if (g == 0) {
        xc[lane] = (red[0][lane] + red[1][lane] + red[2][lane] + red[3][lane])
                   / (float)N_NODES;
    } else if (g == 1) {
        float gacc = bg[lane];
        for (int k = 0; k < F_GLOB; ++k) gacc += gfeat[k] * wg[k * HDIM + lane];
        xc[HDIM + lane] = fmaxf(gacc, 0.f);
    }
    __syncthreads();
    float hacc = 0.f;
    for (int k = g * 32; k < (g + 1) * 32; ++k) hacc += xc[k] * w1[k * HDIM + lane];
    red[g][lane] = hacc;
    __syncthreads();
    if (g == 0)
        hid[lane] = fmaxf(b1[lane] + red[0][lane] + red[1][lane]
                          + red[2][lane] + red[3][lane], 0.f);
    __syncthreads();
    float oacc = 0.f;
    for (int k = g * 16; k < (g + 1) * 16; ++k) oacc += hid[k] * w2[k * OUTDIM + lane];
    red[g][lane] = oacc;
    __syncthreads();
    if (g == 0)
        out[lane] = b2[lane] + red[0][lane] + red[1][lane]
                  + red[2][lane] + red[3][lane];
}

// ---------- launch ----------

extern "C" void kernel_launch(void* const* d_in, const int* in_sizes, int n_in,
                              void* d_out, int out_size, void* d_ws, size_t ws_size,
                              hipStream_t stream) {
    const float* x      = (const float*)d_in[0];
    const int*   eidx   = (const int*)d_in[1];
    const float* gfeat  = (const float*)d_in[2];
    const float* w_node = (const float*)d_in[3];
    const float* b_node = (const float*)d_in[4];
    const float* w_glob = (const float*)d_in[5];
    const float* b_glob = (const float*)d_in[6];
    const float* w_c[3] = {(const float*)d_in[7], (const float*)d_in[9], (const float*)d_in[11]};
    const float* b_c[3] = {(const float*)d_in[8], (const float*)d_in[10], (const float*)d_in[12]};
    const float* w_fc1  = (const float*)d_in[13];
    const float* b_fc1  = (const float*)d_in[14];
    const float* w_fc2  = (const float*)d_in[15];
    const float* b_fc2  = (const float*)d_in[16];
    float* out = (float*)d_out;

    const int* srcp = eidx;
    const int* dstp = eidx + N_EDGES;

    char* ws = (char*)d_ws;
    size_t off = 0;
    auto alloc = [&](size_t bytes) -> void* {
        void* p = ws + off;
        off = (off + bytes + 255) & ~(size_t)255;
        return p;
    };
    int*   rowptr  = (int*)  alloc((size_t)(N_NODES + 1) * 4);
    int*   shcnt   = (int*)  alloc(NSH * 4);
    float* dis     = (float*)alloc((size_t)N_NODES * 4);
    int*   col     = (int*)  alloc((size_t)N_EDGES * 4);
    int2*  stage   = (int2*) alloc((size_t)NSH * SCAP * 8);
    u16*   xb      = (u16*)  alloc((size_t)N_NODES * F_NODE * 2);
    u16*   hbuf    = (u16*)  alloc((size_t)N_NODES * HDIM * 2);
    u16*   hwbuf   = (u16*)  alloc((size_t)N_NODES * HDIM * 2);
    float* partial = (float*)alloc(256 * 64 * 4);

    hipMemsetAsync(shcnt, 0, NSH * 4, stream);

    k_part <<<PBLK, 256, 0, stream>>>(srcp, dstp, shcnt, stage);
    k_build<<<NSH, 1024, 0, stream>>>(stage, shcnt, rowptr, dis, col);

    int mb = (NTILE + 3) / 4;         // 1563 blocks, 4 row-tiles (waves) each
    int cb = ((N_NODES * F_NODE / 8) + 255) / 256;

    k_cvt<<<cb, 256, 0, stream>>>(x, xb);
    // e = x @ wn + bn   (bf16, into hbuf)
    k_mfma<32, true, false><<<mb, 256, 0, stream>>>(xb, w_node, b_node, nullptr, hbuf);
    // hw = dis * (e @ wc0)
    k_mfma<64, false, true><<<mb, 256, 0, stream>>>(hbuf, w_c[0], nullptr, dis, hwbuf);
    k_pull<<<3125, 256, 0, stream>>>(hwbuf, rowptr, col, dis, b_c[0], hbuf);
    for (int l = 1; l < 3; ++l) {
        k_mfma<64, false, true><<<mb, 256, 0, stream>>>(hbuf, w_c[l], nullptr, dis, hwbuf);
        k_pull<<<3125, 256, 0, stream>>>(hwbuf, rowptr, col, dis, b_c[l], hbuf);
    }
    k_mean <<<256, 256, 0, stream>>>(hbuf, partial);
    k_final<<<1, 256, 0, stream>>>(partial, gfeat, w_glob, b_glob,
                                   w_fc1, b_fc1, w_fc2, b_fc2, out);
}